// Round 13
// baseline (370.392 us; speedup 1.0000x reference)
//
#include <hip/hip_runtime.h>
#include <hip/hip_bf16.h>

// Problem constants (GraphGRUCell_62019327754706)
// DTYPES (settled r4/r5): all float tensors FP32 in and out. int32 edges.
// r6: never clamp launch_bounds waves -> spills.
// r8: 4 nodes/wave @ block=256 => VGPR 64, no spill.
// r9: 8 nodes/wave => VGPR 256 + 430MB spill -> never go near 256.
// r11: half-wave node pairing REGRESSED. XCD swizzle WORKED -> keep.
// r12: dense union-range tiling + no-max softmax -> KEEP.
// r13: single-pass padded u16 bins -> fused 190, total 333 = BASE.
// r14/r15: fp16+fdot2 container-failed TWICE -> fdot2 BLACKLISTED.
// r16/r17: quarter-wave phase B CLOSED.
// r18-r21: unroll4 + pk_fma GENUINELY harmful (schedule-fragile dense loops;
//      compiler's rolled schedule wins). Env theory refuted (r21 = 189us).
// r22: idx-only prefetch + parallel mask = NULL (193us). The 4B index was
//      the cheap link; the 8 k-row gathers (L2-thrash misses: FETCH shows
//      ~70MB/iter excess, 5.1MB batch k/v vs 4MB XCD L2) remain on the
//      critical path at each tile top.
// r23 (this): register double-buffer of k-rows -- depth-1 prefetch of next
//      tile's full k-row (8 x uint4 = 32 VGPR) + mask byte, issued right
//      after pl publish so ~900cy miss latency hides under phase B. Idx
//      pipeline deepened to 2. Phase A now straight-line (dummy row-0 dot
//      for invalid lanes, p=0 -> numerics identical). Dot/phaseB/GRU
//      byte-identical. Trades occupancy (VGPR ~96-128) for ILP: the
//      direct mechanism probe for "k-gather latency is the 78us stall".
#define BB 4
#define NN 20000
#define UU 64
#define EE 640000
#define FF 65              // U + D
#define SCALE_F 0.125f     // 1/sqrt(64)
#define PREP_BLOCKS 2500   // (B*N)/32
#define SCAT_BLOCKS 2500   // EE/256

typedef unsigned short u16;
typedef unsigned long long u64;

static inline size_t align_up(size_t x) { return (x + 255) & ~(size_t)255; }

__device__ __forceinline__ float u2f(unsigned int u) { return __uint_as_float(u); }
__device__ __forceinline__ u16 f2bf(float f) {
    __hip_bfloat16 h = __float2bfloat16(f);
    return *reinterpret_cast<u16*>(&h);
}

// ---------------- fat kernel: prep (even blocks) || bin-scatter (odd blocks)
// prep: k,v (bf16) + mask, 8 nodes/wave. scatter: bins[dst*cap+pos]=src.
__global__ __launch_bounds__(256) void prep_scatter_kernel(
    const float* __restrict__ state, const float* __restrict__ inputs,
    const float* __restrict__ Wk, const float* __restrict__ bk,
    const float* __restrict__ Wv, const float* __restrict__ bv,
    u16* __restrict__ kbuf, u16* __restrict__ vbuf,
    unsigned char* __restrict__ maskb,
    const int* __restrict__ edst, const int* __restrict__ esrc,
    int* __restrict__ counts, u16* __restrict__ bins, int cap) {
    int role = blockIdx.x & 1;
    int sub  = blockIdx.x >> 1;
    if (role) {                               // ---- bin-scatter role
        int e = sub * 256 + threadIdx.x;
        if (e < EE) {
            int d = edst[e], s = esrc[e];
            if ((unsigned)d < (unsigned)NN && (unsigned)s < (unsigned)NN) {
                int pos = atomicAdd(&counts[d], 1);
                if (pos < cap) bins[d * cap + pos] = (u16)s;  // clamp: no OOB
            }
        }
        return;
    }
    // ---- prep role
    int w = threadIdx.x >> 6, lane = threadIdx.x & 63;
    int gb = (sub * 4 + w) * 8;               // 8 nodes per wave
    __shared__ float xs[4][8][66];
#pragma unroll
    for (int j = 0; j < 8; ++j) {
        int g = gb + j;
        xs[w][j][lane] = state[(size_t)g * UU + lane];
        if (lane == 0) xs[w][j][64] = inputs[g];
    }
    __syncthreads();                          // uniform (all prep threads reach)

    float ak[8], av[8];
#pragma unroll
    for (int j = 0; j < 8; ++j) { ak[j] = 0.f; av[j] = 0.f; }
    for (int f = 0; f < FF; ++f) {            // weight loaded once, 8 nodes reuse
        float wk = Wk[f * UU + lane], wv = Wv[f * UU + lane];
#pragma unroll
        for (int j = 0; j < 8; ++j) {
            float xv = xs[w][j][f];
            ak[j] += xv * wk; av[j] += xv * wv;
        }
    }
    float bkl = bk[lane], bvl = bv[lane];
#pragma unroll
    for (int j = 0; j < 8; ++j) {
        int g = gb + j;
        kbuf[(size_t)g * UU + lane] = f2bf(ak[j] + bkl);
        vbuf[(size_t)g * UU + lane] = f2bf(av[j] + bvl);
        if (lane == 0) maskb[g] = (xs[w][j][58] != 0.0f) ? 1 : 0;
    }
}

// -------------------- fused: 4 nodes/wave, union tiling over bins, GRU
__global__ __launch_bounds__(256) void fused_fast(
    const float* __restrict__ state, const float* __restrict__ inputs,
    const float* __restrict__ Wq, const float* __restrict__ bq,
    const float* __restrict__ Ws, const float* __restrict__ bs,
    const float* __restrict__ W1, const float* __restrict__ b1,
    const float* __restrict__ W2, const float* __restrict__ b2,
    const u16* __restrict__ kbuf, const u16* __restrict__ vbuf,
    const unsigned char* __restrict__ maskb,
    const int* __restrict__ counts, const u16* __restrict__ bins, int cap,
    float* __restrict__ out) {
    int w = threadIdx.x >> 6, lane = threadIdx.x & 63;
    int hl = lane & 31, hf = lane >> 5;

    // XCD-aware swizzle: batch b pinned to XCDs {2b, 2b+1} (r11: FETCH -29%).
    // grid = 5000 = 625*8, dispatch round-robins XCD = bid%8 -> bijective.
    int bid = blockIdx.x;
    int xcd = bid & 7;
    int b   = xcd >> 1;                            // batch 0..3
    int ib  = ((bid >> 3) << 1) | (xcd & 1);       // block-in-batch 0..1249
    int gb  = b * NN + ib * 16 + w * 4;            // 4 consecutive nodes/wave

    __shared__ float xs[4][4][66];            // x rows; later h2 rows
    __shared__ float qs[4][4][68];            // q rows (68: 4-bank row skew)
    __shared__ u64   pl[4][64];               // per-wave {srow,p} publish

#pragma unroll
    for (int j = 0; j < 4; ++j) {
        int g = gb + j;
        xs[w][j][lane] = state[(size_t)g * UU + lane];
        if (lane == 0) xs[w][j][64] = inputs[g];
    }
    __syncthreads();                          // A (uniform)

    // q (pre-scaled) + sproj for 4 nodes; weight value loaded once
    float aq[4], as_[4];
#pragma unroll
    for (int j = 0; j < 4; ++j) { aq[j] = 0.f; as_[j] = 0.f; }
    for (int f = 0; f < FF; ++f) {
        float wq = Wq[f * UU + lane], ws = Ws[f * UU + lane];
#pragma unroll
        for (int j = 0; j < 4; ++j) {
            float xv = xs[w][j][f];
            aq[j] += xv * wq; as_[j] += xv * ws;
        }
    }
    float bql = bq[lane], bsl = bs[lane];
#pragma unroll
    for (int j = 0; j < 4; ++j) {
        as_[j] += bsl;
        qs[w][j][lane] = (aq[j] + bql) * SCALE_F;
    }
    __syncthreads();                          // B (uniform)

    bool mg[4];
#pragma unroll
    for (int j = 0; j < 4; ++j) mg[j] = (xs[w][j][58] != 0.0f);

    const unsigned char* mb = maskb + (size_t)b * NN;
    const u16* kb = kbuf + (size_t)b * NN * UU;
    const u16* vb = vbuf + (size_t)b * NN * UU;
    int nb = gb - b * NN;                     // node base within batch

    // virtual concatenated span over the 4 nodes' bins
    int cum[5]; cum[0] = 0;
    int ebase[4];
#pragma unroll
    for (int j = 0; j < 4; ++j) {
        int dg = counts[nb + j];
        dg = min(max(dg, 0), cap);
        if (!mg[j]) dg = 0;                   // masked dst: skip entire bin
        cum[j + 1] = cum[j] + dg;
        ebase[j] = (nb + j) * cap - cum[j];   // bins addr = ebase[j] + i
    }
    int total = cum[4];

    // accumulators: lane hl holds channels (2hl, 2hl+1) of its half's slots
    float acE[4], acO[4], l[4];
#pragma unroll
    for (int j = 0; j < 4; ++j) { acE[j] = 0.f; acO[j] = 0.f; l[j] = 0.f; }

    const unsigned* vbw = (const unsigned*)vb; // bf16 channel-pair view

    // --- pipeline prologue: tile0 idx + k-rows + mask; tile1 idx.
    // All in named regs. Invalid lanes use row 0 (always in-bounds, p=0).
    int sC = 0, jlC = 0; bool vC = (lane < total);
    if (vC) { jlC = (lane >= cum[1]) + (lane >= cum[2]) + (lane >= cum[3]);
              sC = bins[ebase[jlC] + lane]; }
    unsigned char mC = mb[sC];
    const uint4* kpC = (const uint4*)(kb + ((size_t)sC << 6));
    uint4 k0 = kpC[0], k1 = kpC[1], k2 = kpC[2], k3 = kpC[3],
          k4 = kpC[4], k5 = kpC[5], k6 = kpC[6], k7 = kpC[7];
    int sN = 0, jlN = 0; bool vN = (64 + lane < total);
    if (vN) { int i1 = 64 + lane;
              jlN = (i1 >= cum[1]) + (i1 >= cum[2]) + (i1 >= cum[3]);
              sN = bins[ebase[jlN] + i1]; }

#pragma unroll 1
    for (int tbase = 0; tbase < total; tbase += 64) {
        // issue idx prefetch for tile t+2 (needed next iter's k-prefetch)
        int i2 = tbase + 128 + lane;
        bool v2 = (i2 < total);
        int jl2 = 0, s2 = 0;
        if (v2) { jl2 = (i2 >= cum[1]) + (i2 >= cum[2]) + (i2 >= cum[3]);
                  s2 = bins[ebase[jl2] + i2]; }

        // ---- phase A: straight-line dot from prefetched regs + LDS q
        {
            const float* qrow = &qs[w][0][0] + jlC * 68;
            float d0 = 0.f, d1 = 0.f, d2 = 0.f, d3 = 0.f;
            const float4 qa0 = *(const float4*)&qrow[0];
            const float4 qb0 = *(const float4*)&qrow[4];
            d0 += u2f(k0.x << 16) * qa0.x; d1 += u2f(k0.x & 0xFFFF0000u) * qa0.y;
            d2 += u2f(k0.y << 16) * qa0.z; d3 += u2f(k0.y & 0xFFFF0000u) * qa0.w;
            d0 += u2f(k0.z << 16) * qb0.x; d1 += u2f(k0.z & 0xFFFF0000u) * qb0.y;
            d2 += u2f(k0.w << 16) * qb0.z; d3 += u2f(k0.w & 0xFFFF0000u) * qb0.w;
            const float4 qa1 = *(const float4*)&qrow[8];
            const float4 qb1 = *(const float4*)&qrow[12];
            d0 += u2f(k1.x << 16) * qa1.x; d1 += u2f(k1.x & 0xFFFF0000u) * qa1.y;
            d2 += u2f(k1.y << 16) * qa1.z; d3 += u2f(k1.y & 0xFFFF0000u) * qa1.w;
            d0 += u2f(k1.z << 16) * qb1.x; d1 += u2f(k1.z & 0xFFFF0000u) * qb1.y;
            d2 += u2f(k1.w << 16) * qb1.z; d3 += u2f(k1.w & 0xFFFF0000u) * qb1.w;
            const float4 qa2 = *(const float4*)&qrow[16];
            const float4 qb2 = *(const float4*)&qrow[20];
            d0 += u2f(k2.x << 16) * qa2.x; d1 += u2f(k2.x & 0xFFFF0000u) * qa2.y;
            d2 += u2f(k2.y << 16) * qa2.z; d3 += u2f(k2.y & 0xFFFF0000u) * qa2.w;
            d0 += u2f(k2.z << 16) * qb2.x; d1 += u2f(k2.z & 0xFFFF0000u) * qb2.y;
            d2 += u2f(k2.w << 16) * qb2.z; d3 += u2f(k2.w & 0xFFFF0000u) * qb2.w;
            const float4 qa3 = *(const float4*)&qrow[24];
            const float4 qb3 = *(const float4*)&qrow[28];
            d0 += u2f(k3.x << 16) * qa3.x; d1 += u2f(k3.x & 0xFFFF0000u) * qa3.y;
            d2 += u2f(k3.y << 16) * qa3.z; d3 += u2f(k3.y & 0xFFFF0000u) * qa3.w;
            d0 += u2f(k3.z << 16) * qb3.x; d1 += u2f(k3.z & 0xFFFF0000u) * qb3.y;
            d2 += u2f(k3.w << 16) * qb3.z; d3 += u2f(k3.w & 0xFFFF0000u) * qb3.w;
            const float4 qa4 = *(const float4*)&qrow[32];
            const float4 qb4 = *(const float4*)&qrow[36];
            d0 += u2f(k4.x << 16) * qa4.x; d1 += u2f(k4.x & 0xFFFF0000u) * qa4.y;
            d2 += u2f(k4.y << 16) * qa4.z; d3 += u2f(k4.y & 0xFFFF0000u) * qa4.w;
            d0 += u2f(k4.z << 16) * qb4.x; d1 += u2f(k4.z & 0xFFFF0000u) * qb4.y;
            d2 += u2f(k4.w << 16) * qb4.z; d3 += u2f(k4.w & 0xFFFF0000u) * qb4.w;
            const float4 qa5 = *(const float4*)&qrow[40];
            const float4 qb5 = *(const float4*)&qrow[44];
            d0 += u2f(k5.x << 16) * qa5.x; d1 += u2f(k5.x & 0xFFFF0000u) * qa5.y;
            d2 += u2f(k5.y << 16) * qa5.z; d3 += u2f(k5.y & 0xFFFF0000u) * qa5.w;
            d0 += u2f(k5.z << 16) * qb5.x; d1 += u2f(k5.z & 0xFFFF0000u) * qb5.y;
            d2 += u2f(k5.w << 16) * qb5.z; d3 += u2f(k5.w & 0xFFFF0000u) * qb5.w;
            const float4 qa6 = *(const float4*)&qrow[48];
            const float4 qb6 = *(const float4*)&qrow[52];
            d0 += u2f(k6.x << 16) * qa6.x; d1 += u2f(k6.x & 0xFFFF0000u) * qa6.y;
            d2 += u2f(k6.y << 16) * qa6.z; d3 += u2f(k6.y & 0xFFFF0000u) * qa6.w;
            d0 += u2f(k6.z << 16) * qb6.x; d1 += u2f(k6.z & 0xFFFF0000u) * qb6.y;
            d2 += u2f(k6.w << 16) * qb6.z; d3 += u2f(k6.w & 0xFFFF0000u) * qb6.w;
            const float4 qa7 = *(const float4*)&qrow[56];
            const float4 qb7 = *(const float4*)&qrow[60];
            d0 += u2f(k7.x << 16) * qa7.x; d1 += u2f(k7.x & 0xFFFF0000u) * qa7.y;
            d2 += u2f(k7.y << 16) * qa7.z; d3 += u2f(k7.y & 0xFFFF0000u) * qa7.w;
            d0 += u2f(k7.z << 16) * qb7.x; d1 += u2f(k7.z & 0xFFFF0000u) * qb7.y;
            d2 += u2f(k7.w << 16) * qb7.z; d3 += u2f(k7.w & 0xFFFF0000u) * qb7.w;
            float sc = (d0 + d1) + (d2 + d3);
            float p = (vC && mC) ? __expf(sc) : 0.f;   // no-max softmax
            pl[w][lane] = ((u64)(unsigned)sC << 32) | (u64)__float_as_uint(p);
        }
        __builtin_amdgcn_wave_barrier();

        // issue k-row + mask prefetch for tile t+1 (hides under phase B)
        const uint4* kpN = (const uint4*)(kb + ((size_t)sN << 6));
        uint4 n0 = kpN[0], n1 = kpN[1], n2 = kpN[2], n3 = kpN[3],
              n4 = kpN[4], n5 = kpN[5], n6 = kpN[6], n7 = kpN[7];
        unsigned char mN = mb[sN];

        // ---- phase B: half-wave slot pairing; lane hl = channels 2hl,2hl+1
#pragma unroll
        for (int j = 0; j < 4; ++j) {
            int lo = max(cum[j], tbase);
            int hi = min(cum[j + 1], tbase + 64);
#pragma unroll 1
            for (int s0 = lo; s0 < hi; s0 += 8) {
#pragma unroll
                for (int k2_ = 0; k2_ < 4; ++k2_) {
                    int ss = s0 + 2 * k2_ + hf;
                    int sidx = min(ss, hi - 1) - tbase;
                    u64 pk = pl[w][sidx];     // broadcast per half
                    float pj = (ss < hi) ? u2f((unsigned)pk) : 0.f;
                    unsigned sj = (unsigned)(pk >> 32);
                    unsigned v2v = vbw[(sj << 5) | (unsigned)hl];  // 2 channels
                    acE[j] += pj * u2f(v2v << 16);
                    acO[j] += pj * u2f(v2v & 0xFFFF0000u);
                    l[j]   += pj;
                }
            }
        }
        __builtin_amdgcn_wave_barrier();

        // rotate pipeline registers
        k0 = n0; k1 = n1; k2 = n2; k3 = n3;
        k4 = n4; k5 = n5; k6 = n6; k7 = n7;
        mC = mN; vC = vN; jlC = jlN; sC = sN;
        sN = s2; jlN = jl2; vN = v2;
    }

    // finalize: combine halves, remap channel-pair layout -> lane=channel
#pragma unroll
    for (int j = 0; j < 4; ++j) {
        float lj = l[j]   + __shfl_xor(l[j],   32, 64);
        float aE = acE[j] + __shfl_xor(acE[j], 32, 64);
        float aO = acO[j] + __shfl_xor(acO[j], 32, 64);
        float vE = __shfl(aE, lane >> 1, 64);
        float vO = __shfl(aO, lane >> 1, 64);
        float acc = (lane & 1) ? vO : vE;
        float agg = (lj > 0.f) ? acc / fmaxf(lj, 1e-16f) : 0.f;
        float h2 = mg[j] ? (agg + as_[j]) : xs[w][j][lane];  // masked: pass h
        xs[w][j][lane] = h2;                  // own slot; [64]=xin preserved
    }
    __syncthreads();                          // C (uniform)

    // GRU: value = sigmoid([xin,h2]@W1+b1), c = tanh([xin,r*h2]@W2+b2)
    float xin[4];
#pragma unroll
    for (int j = 0; j < 4; ++j) xin[j] = xs[w][j][64];
    float a1v[4], a2v[4];
#pragma unroll
    for (int j = 0; j < 4; ++j) { a1v[j] = xin[j] * W1[lane]; a2v[j] = xin[j] * W1[UU + lane]; }
    for (int f = 0; f < UU; ++f) {
        float w1a = W1[(f + 1) * 128 + lane], w1b = W1[(f + 1) * 128 + UU + lane];
#pragma unroll
        for (int j = 0; j < 4; ++j) {
            float hv = xs[w][j][f];
            a1v[j] += hv * w1a; a2v[j] += hv * w1b;
        }
    }
    float b1a = b1[lane], b1b = b1[UU + lane];
    float rst[4], z[4];
#pragma unroll
    for (int j = 0; j < 4; ++j) {
        rst[j] = 1.f / (1.f + __expf(-(a1v[j] + b1a)));
        z[j]   = 1.f / (1.f + __expf(-(a2v[j] + b1b)));
        qs[w][j][lane] = rst[j] * xs[w][j][lane];   // reset*h2
    }
    __syncthreads();                          // D (uniform)

    float a3v[4];
#pragma unroll
    for (int j = 0; j < 4; ++j) a3v[j] = xin[j] * W2[lane];
    for (int f = 0; f < UU; ++f) {
        float w2v = W2[(f + 1) * UU + lane];
#pragma unroll
        for (int j = 0; j < 4; ++j) a3v[j] += qs[w][j][f] * w2v;
    }
    float b2l = b2[lane];
#pragma unroll
    for (int j = 0; j < 4; ++j) {
        float a = a3v[j] + b2l;
        float aa = fabsf(a), tt = __expf(-2.f * aa);
        float c = copysignf((1.f - tt) / (1.f + tt), a);
        float h2v_ = xs[w][j][lane];
        out[(size_t)(gb + j) * UU + lane] = (1.f - z[j]) * h2v_ + z[j] * c;
    }
}

// ------------------------------------------------------------------- launch
extern "C" void kernel_launch(void* const* d_in, const int* in_sizes, int n_in,
                              void* d_out, int out_size, void* d_ws, size_t ws_size,
                              hipStream_t stream) {
    const float* inputs = (const float*)d_in[0];
    const float* state  = (const float*)d_in[1];
    if (in_sizes[0] != BB * NN) { inputs = (const float*)d_in[1]; state = (const float*)d_in[0]; }
    const int*   esrc   = (const int*)d_in[2];
    const int*   edst   = (const int*)d_in[3];
    const float* Wq = (const float*)d_in[4];
    const float* bq = (const float*)d_in[5];
    const float* Wk = (const float*)d_in[6];
    const float* bk = (const float*)d_in[7];
    const float* Wv = (const float*)d_in[8];
    const float* bv = (const float*)d_in[9];
    const float* Ws = (const float*)d_in[10];
    const float* bs = (const float*)d_in[11];
    const float* W1 = (const float*)d_in[12];
    const float* b1 = (const float*)d_in[13];
    const float* W2 = (const float*)d_in[14];
    const float* b2 = (const float*)d_in[15];
    float* out = (float*)d_out;

    // workspace carve: fixed parts first, bins take the remainder (cap sized
    // from ws_size; cap=64 needs exactly the r8-proven footprint, cap<=128).
    char* base = (char*)d_ws;
    size_t ofs = 0;
    int* counts = (int*)(base + ofs); ofs = align_up(ofs + (size_t)NN * 4);
    unsigned char* maskb = (unsigned char*)(base + ofs); ofs = align_up(ofs + (size_t)BB * NN);
    u16* kbuf = (u16*)(base + ofs); ofs = align_up(ofs + (size_t)BB * NN * UU * 2);
    u16* vbuf = (u16*)(base + ofs); ofs = align_up(ofs + (size_t)BB * NN * UU * 2);
    u16* bins = (u16*)(base + ofs);
    size_t avail = (ws_size > ofs) ? (ws_size - ofs) : 0;
    int cap = (int)(avail / ((size_t)NN * 2));
    if (cap > 128) cap = 128;
    if (cap < 64)  cap = 64;   // r8-proven budget guarantees this fits
    (void)n_in; (void)out_size;

    hipMemsetAsync(counts, 0, (size_t)NN * 4, stream);
    prep_scatter_kernel<<<PREP_BLOCKS + SCAT_BLOCKS, 256, 0, stream>>>(
        state, inputs, Wk, bk, Wv, bv, kbuf, vbuf, maskb,
        edst, esrc, counts, bins, cap);
    fused_fast<<<(BB * NN) / 16, 256, 0, stream>>>(state, inputs, Wq, bq,
                                                   Ws, bs, W1, b1, W2, b2,
                                                   kbuf, vbuf, maskb,
                                                   counts, bins, cap, out);
}